// Round 8
// baseline (576.908 us; speedup 1.0000x reference)
//
#include <hip/hip_runtime.h>
#include <hip/hip_bf16.h>
#include <math.h>

#define N_NODES 100000
#define N_EDGES 1600000
#define D_IN 64
#define D_HID 64
#define D_OUT 40
#define NBLK ((N_NODES + 255) / 256)   // 391 scan blocks
#define GRP_SZ (N_NODES / 8)           // 12500 targets per XCD group

typedef __hip_bfloat16 bf16;

__device__ __forceinline__ float bflo(unsigned int u) {
    union { unsigned int i; float f; } c; c.i = u << 16; return c.f;
}
__device__ __forceinline__ float bfhi(unsigned int u) {
    union { unsigned int i; float f; } c; c.i = u & 0xFFFF0000u; return c.f;
}

// ---- zero ints (no hipMemsetAsync) ----
__global__ __launch_bounds__(256) void k_zero(int* __restrict__ p, int n) {
    int i = blockIdx.x * 256 + threadIdx.x;
    if (i < n) p[i] = 0;
}

// ---- XCD-partitioned in-degree histogram: group g owns targets [g*GRP_SZ, ...) ----
__global__ __launch_bounds__(256) void k_deg_p(const int* __restrict__ col,
                                               int* __restrict__ deg) {
    int grp = blockIdx.x & 7;          // round-robin -> XCD (perf heuristic only)
    int sub = blockIdx.x >> 3;         // 0..31
    int lo = grp * GRP_SZ, hi = lo + GRP_SZ;
    for (int e = sub * 256 + threadIdx.x; e < N_EDGES; e += 32 * 256) {
        int c = col[e];
        if (c >= lo && c < hi) atomicAdd(&deg[c], 1);
    }
}

// ---- dinv = rsqrt(deg + 1) ----
__global__ __launch_bounds__(256) void k_dinv(const int* __restrict__ deg,
                                              float* __restrict__ dinv) {
    int v = blockIdx.x * 256 + threadIdx.x;
    if (v < N_NODES) dinv[v] = rsqrtf((float)deg[v] + 1.0f);
}

// ---- scan pass 1: per-block sums of deg ----
__global__ __launch_bounds__(256) void k_bsum(const int* __restrict__ deg,
                                              int* __restrict__ bsum) {
    __shared__ int sm[256];
    int i = blockIdx.x * 256 + threadIdx.x;
    sm[threadIdx.x] = (i < N_NODES) ? deg[i] : 0;
    __syncthreads();
    for (int s = 128; s > 0; s >>= 1) {
        if (threadIdx.x < s) sm[threadIdx.x] += sm[threadIdx.x + s];
        __syncthreads();
    }
    if (threadIdx.x == 0) bsum[blockIdx.x] = sm[0];
}

// ---- scan pass 2: exclusive scan of block sums (single block) ----
__global__ __launch_bounds__(512) void k_scanb(int* __restrict__ bsum) {
    __shared__ int sm[512];
    int t = threadIdx.x;
    sm[t] = (t < NBLK) ? bsum[t] : 0;
    __syncthreads();
    for (int off = 1; off < 512; off <<= 1) {
        int v = (t >= off) ? sm[t - off] : 0;
        __syncthreads();
        sm[t] += v;
        __syncthreads();
    }
    if (t < NBLK) bsum[t] = (t > 0) ? sm[t - 1] : 0;
}

// ---- scan pass 3: per-block exclusive scan + block offset -> start[] ----
__global__ __launch_bounds__(256) void k_scanf(const int* __restrict__ deg,
                                               const int* __restrict__ boff,
                                               int* __restrict__ start) {
    __shared__ int sm[256];
    int i = blockIdx.x * 256 + threadIdx.x;
    int v = (i < N_NODES) ? deg[i] : 0;
    sm[threadIdx.x] = v;
    __syncthreads();
    for (int off = 1; off < 256; off <<= 1) {
        int u = (threadIdx.x >= off) ? sm[threadIdx.x - off] : 0;
        __syncthreads();
        sm[threadIdx.x] += u;
        __syncthreads();
    }
    int excl = sm[threadIdx.x] - v + boff[blockIdx.x];
    if (i < N_NODES) start[i] = excl;
    if (i == N_NODES - 1) start[N_NODES] = excl + v;
}

// ---- XCD-partitioned bucket: group g scatters only into its csr slice ----
__global__ __launch_bounds__(256) void k_bucket_p(const int* __restrict__ ei,
                                                  const int* __restrict__ start,
                                                  int* __restrict__ cnt,
                                                  int* __restrict__ csr) {
    int grp = blockIdx.x & 7;
    int sub = blockIdx.x >> 3;
    int lo = grp * GRP_SZ, hi = lo + GRP_SZ;
    for (int e = sub * 256 + threadIdx.x; e < N_EDGES; e += 32 * 256) {
        int c = ei[N_EDGES + e];
        if (c >= lo && c < hi) {
            int r = ei[e];
            int p = atomicAdd(&cnt[c], 1);
            csr[start[c] + p] = r;
        }
    }
}

// ---- layer1 GEMM: gb[v,j] = bf16( dinv[v] * sum_k x[v,k]*W1[k,j] ) ----
__global__ __launch_bounds__(256) void k_gemm1(const float* __restrict__ x,
                                               const float* __restrict__ W,
                                               const float* __restrict__ dinv,
                                               bf16* __restrict__ gb) {
    __shared__ float Ws[64 * 64];
    __shared__ float xs[4][64];
    int tid = threadIdx.x;
    for (int i = tid; i < 64 * 64; i += 256) Ws[i] = W[i];
    int v0 = blockIdx.x * 4;
    for (int i = tid; i < 4 * 64; i += 256) xs[i >> 6][i & 63] = x[v0 * 64 + i];
    __syncthreads();
    int r = tid >> 6, j = tid & 63;
    float acc = 0.f;
#pragma unroll
    for (int k = 0; k < 64; k++) acc += xs[r][k] * Ws[k * 64 + j];
    int v = v0 + r;
    gb[v * 64 + j] = __float2bfloat16(acc * dinv[v]);
}

// ---- agg1: half-wave per edge, uint (2xbf16) gathers; bias+ReLU -> h ----
__global__ __launch_bounds__(256) void k_agg1(const int* __restrict__ csr,
                                              const int* __restrict__ start,
                                              const unsigned int* __restrict__ gb2,  // N*32 uints
                                              const float* __restrict__ dinv,
                                              const float* __restrict__ b1,
                                              float* __restrict__ h) {
    int lane = threadIdx.x & 63;
    int half = lane >> 5;            // 0/1: which edge of the pair
    int l = lane & 31;               // channel-pair index (covers 2l, 2l+1)
    int v = blockIdx.x * 4 + (threadIdx.x >> 6);
    int s = start[v], e2 = start[v + 1];
    float ax = 0.f, ay = 0.f;
    if (half == 0) {                 // self-loop message added once
        unsigned int u = gb2[v * 32 + l];
        ax = bflo(u); ay = bfhi(u);
    }
    for (int base = s; base < e2; base += 64) {
        int cnt = e2 - base; if (cnt > 64) cnt = 64;
        int rl = (lane < cnt) ? csr[base + lane] : 0;  // coalesced index prefetch
#pragma unroll 8
        for (int i = 0; i < 32; i++) {
            int idx = 2 * i + half;
            int r = __shfl(rl, idx, 64);
            if (idx < cnt) {
                unsigned int u = gb2[r * 32 + l];
                ax += bflo(u); ay += bfhi(u);
            }
        }
    }
    ax += __shfl_xor(ax, 32, 64);    // merge the two half-wave partials
    ay += __shfl_xor(ay, 32, 64);
    float d = dinv[v];
    float hx = d * ax + b1[2 * l];
    float hy = d * ay + b1[2 * l + 1];
    hx = hx > 0.f ? hx : 0.f;
    hy = hy > 0.f ? hy : 0.f;
    if (half == 0) ((float2*)(h + (size_t)v * 64))[l] = make_float2(hx, hy);
}

// ---- layer2 GEMM: g2b[v,j] = bf16( dinv[v] * sum_k h[v,k]*W2[k,j] ) ----
__global__ __launch_bounds__(256) void k_gemm2(const float* __restrict__ h,
                                               const float* __restrict__ W,
                                               const float* __restrict__ dinv,
                                               bf16* __restrict__ g2b) {
    __shared__ float Ws[64 * 40];
    __shared__ float hs[4][64];
    int tid = threadIdx.x;
    for (int i = tid; i < 64 * 40; i += 256) Ws[i] = W[i];
    int v0 = blockIdx.x * 4;
    for (int i = tid; i < 4 * 64; i += 256) hs[i >> 6][i & 63] = h[v0 * 64 + i];
    __syncthreads();
    int r = tid >> 6, j = tid & 63;
    if (j < 40) {
        float acc = 0.f;
#pragma unroll
        for (int k = 0; k < 64; k++) acc += hs[r][k] * Ws[k * 40 + j];
        int v = v0 + r;
        g2b[v * 40 + j] = __float2bfloat16(acc * dinv[v]);
    }
}

// ---- agg2: half-wave per edge; fused bias + log_softmax -> out (float2) ----
__global__ __launch_bounds__(256) void k_agg2(const int* __restrict__ csr,
                                              const int* __restrict__ start,
                                              const unsigned int* __restrict__ g2b2, // N*20 uints
                                              const float* __restrict__ dinv,
                                              const float* __restrict__ b2v,
                                              float* __restrict__ out) {
    int lane = threadIdx.x & 63;
    int half = lane >> 5;
    int l = lane & 31;               // pair index; l<20 carries channels
    int v = blockIdx.x * 4 + (threadIdx.x >> 6);
    int s = start[v], e2 = start[v + 1];
    bool act = (l < 20);
    float ax = 0.f, ay = 0.f;
    if (half == 0 && act) {
        unsigned int u = g2b2[v * 20 + l];
        ax = bflo(u); ay = bfhi(u);
    }
    for (int base = s; base < e2; base += 64) {
        int cnt = e2 - base; if (cnt > 64) cnt = 64;
        int rl = (lane < cnt) ? csr[base + lane] : 0;
#pragma unroll 8
        for (int i = 0; i < 32; i++) {
            int idx = 2 * i + half;
            int r = __shfl(rl, idx, 64);
            if (act && idx < cnt) {
                unsigned int u = g2b2[r * 20 + l];
                ax += bflo(u); ay += bfhi(u);
            }
        }
    }
    ax += __shfl_xor(ax, 32, 64);
    ay += __shfl_xor(ay, 32, 64);
    float d = dinv[v];
    float lx = act ? d * ax + b2v[2 * l] : -INFINITY;
    float ly = act ? d * ay + b2v[2 * l + 1] : -INFINITY;
    float m = fmaxf(lx, ly);
#pragma unroll
    for (int o = 16; o > 0; o >>= 1) m = fmaxf(m, __shfl_xor(m, o, 64));
    float ex = act ? (expf(lx - m) + expf(ly - m)) : 0.f;
#pragma unroll
    for (int o = 16; o > 0; o >>= 1) ex += __shfl_xor(ex, o, 64);
    float lse = m + logf(ex);
    if (half == 0 && act)
        ((float2*)(out + (size_t)v * 40))[l] = make_float2(lx - lse, ly - lse);
}

extern "C" void kernel_launch(void* const* d_in, const int* in_sizes, int n_in,
                              void* d_out, int out_size, void* d_ws, size_t ws_size,
                              hipStream_t stream) {
    const float* x  = (const float*)d_in[0];
    const int*   ei = (const int*)d_in[1];
    const float* W1 = (const float*)d_in[2];
    const float* b1 = (const float*)d_in[3];
    const float* W2 = (const float*)d_in[4];
    const float* b2 = (const float*)d_in[5];
    float* out = (float*)d_out;

    const int N = N_NODES;
    // Workspace ~47 MB.
    int*   deg   = (int*)d_ws;                  // N
    int*   cnt   = deg + N;                     // N (adjacent -> one zero pass)
    int*   start = cnt + N;                     // N+1
    int*   bsum  = start + N + 1;               // 512
    int*   csr   = bsum + 512;                  // E
    float* dinv  = (float*)(csr + N_EDGES);     // N
    bf16*  gb    = (bf16*)(dinv + N);           // N*64 bf16 (g1; reused as g2 N*40)
    float* h     = (float*)(gb + (size_t)N * 64); // N*64 fp32

    k_zero<<<(2 * N + 255) / 256, 256, 0, stream>>>(deg, 2 * N);
    k_deg_p<<<256, 256, 0, stream>>>(ei + N_EDGES, deg);
    k_dinv<<<NBLK, 256, 0, stream>>>(deg, dinv);
    k_bsum<<<NBLK, 256, 0, stream>>>(deg, bsum);
    k_scanb<<<1, 512, 0, stream>>>(bsum);
    k_scanf<<<NBLK, 256, 0, stream>>>(deg, bsum, start);
    k_bucket_p<<<256, 256, 0, stream>>>(ei, start, cnt, csr);
    k_gemm1<<<N / 4, 256, 0, stream>>>(x, W1, dinv, gb);
    k_agg1<<<N / 4, 256, 0, stream>>>(csr, start, (const unsigned int*)gb, dinv, b1, h);
    k_gemm2<<<N / 4, 256, 0, stream>>>(h, W2, dinv, gb);
    k_agg2<<<N / 4, 256, 0, stream>>>(csr, start, (const unsigned int*)gb, dinv, b2, out);
}

// Round 9
// 391.614 us; speedup vs baseline: 1.4732x; 1.4732x over previous
//
#include <hip/hip_runtime.h>
#include <hip/hip_bf16.h>
#include <math.h>

#define N_NODES 100000
#define N_EDGES 1600000
#define D_IN 64
#define D_HID 64
#define D_OUT 40
#define NBUCK 256
#define BSZ 391                 // nodes per bucket; 256*391 = 100096 >= N
#define P3_EPB 4096             // edges per k_place block
#define P3_GRID ((N_EDGES + P3_EPB - 1) / P3_EPB)   // 391

typedef __hip_bfloat16 bf16;

__device__ __forceinline__ float bflo(unsigned int u) {
    union { unsigned int i; float f; } c; c.i = u << 16; return c.f;
}
__device__ __forceinline__ float bfhi(unsigned int u) {
    union { unsigned int i; float f; } c; c.i = u & 0xFFFF0000u; return c.f;
}

// ---- zero ints ----
__global__ __launch_bounds__(256) void k_zero(int* __restrict__ p, int n) {
    int i = blockIdx.x * 256 + threadIdx.x;
    if (i < n) p[i] = 0;
}

// ---- phase 1: global bucket counts (LDS histogram, padded global counters) ----
__global__ __launch_bounds__(256) void k_cnt(const int* __restrict__ col,
                                             int* __restrict__ bcnt_p) {
    __shared__ int hist[NBUCK];
    hist[threadIdx.x] = 0;
    __syncthreads();
    for (int e = blockIdx.x * 256 + threadIdx.x; e < N_EDGES; e += 256 * 256) {
        unsigned int c = (unsigned int)col[e];
        atomicAdd(&hist[c / 391u], 1);
    }
    __syncthreads();
    int hv = hist[threadIdx.x];
    if (hv) atomicAdd(&bcnt_p[threadIdx.x * 16], hv);   // 64B-strided: no line sharing
}

// ---- phase 2: scan 256 bucket counts; init fill = base ----
__global__ __launch_bounds__(256) void k_scan256(const int* __restrict__ bcnt_p,
                                                 int* __restrict__ fill_p,
                                                 int* __restrict__ bucket_base) {
    __shared__ int sm[256];
    int t = threadIdx.x;
    int v = bcnt_p[t * 16];
    sm[t] = v;
    __syncthreads();
    for (int off = 1; off < 256; off <<= 1) {
        int u = (t >= off) ? sm[t - off] : 0;
        __syncthreads();
        sm[t] += u;
        __syncthreads();
    }
    int excl = sm[t] - v;
    bucket_base[t] = excl;
    fill_p[t * 16] = excl;
    if (t == 255) bucket_base[256] = sm[255];
}

// ---- phase 3: partition edges into bucket-contiguous packed array ----
// packed part[] word: (local_c << 17) | src   (9 + 17 = 26 bits)
__global__ __launch_bounds__(256) void k_place(const int* __restrict__ ei,
                                               int* __restrict__ fill_p,
                                               int* __restrict__ part) {
    __shared__ int cnt_l[NBUCK];
    __shared__ int base_l[NBUCK];
    cnt_l[threadIdx.x] = 0;
    __syncthreads();
    int e0 = blockIdx.x * P3_EPB;
    unsigned int meta[16];                     // (b<<21)|(lc<<12)|slot
#pragma unroll
    for (int k = 0; k < 16; k++) {
        int e = e0 + k * 256 + threadIdx.x;
        if (e < N_EDGES) {
            unsigned int c = (unsigned int)ei[N_EDGES + e];
            unsigned int b = c / 391u;
            unsigned int lc = c - b * 391u;
            unsigned int slot = atomicAdd(&cnt_l[b], 1);   // slot < 4096
            meta[k] = (b << 21) | (lc << 12) | slot;
        } else meta[k] = 0xFFFFFFFFu;
    }
    __syncthreads();
    int cv = cnt_l[threadIdx.x];
    if (cv) base_l[threadIdx.x] = atomicAdd(&fill_p[threadIdx.x * 16], cv);
    __syncthreads();
#pragma unroll
    for (int k = 0; k < 16; k++) {
        if (meta[k] != 0xFFFFFFFFu) {
            int e = e0 + k * 256 + threadIdx.x;
            unsigned int b = meta[k] >> 21;
            unsigned int lc = (meta[k] >> 12) & 0x1FFu;
            unsigned int slot = meta[k] & 0xFFFu;
            unsigned int r = (unsigned int)ei[e];
            part[base_l[b] + slot] = (int)((lc << 17) | r);
        }
    }
}

// ---- phase 4: per-bucket CSR build + deg/start/dinv, all in LDS/L2 ----
__global__ __launch_bounds__(256) void k_build(const int* __restrict__ part,
                                               const int* __restrict__ bucket_base,
                                               int* __restrict__ start,
                                               float* __restrict__ dinv,
                                               int* __restrict__ csr) {
    __shared__ int deg_l[392];
    __shared__ int excl_l[392];
    int tid = threadIdx.x;
    int b = blockIdx.x;
    int base = bucket_base[b], end = bucket_base[b + 1];
    int m = end - base;
    for (int i = tid; i < 392; i += 256) deg_l[i] = 0;
    __syncthreads();
    for (int i = tid; i < m; i += 256)
        atomicAdd(&deg_l[(unsigned int)part[base + i] >> 17], 1);
    __syncthreads();
    // wave 0: exclusive scan of deg_l[0..391]
    if (tid < 64) {
        int carry = 0;
        for (int ch = 0; ch < 7; ch++) {       // 7*64 = 448 >= 392
            int idx = ch * 64 + tid;
            int val = (idx < 392) ? deg_l[idx] : 0;
            int incl = val;
#pragma unroll
            for (int off = 1; off < 64; off <<= 1) {
                int u = __shfl_up(incl, off, 64);
                if (tid >= off) incl += u;
            }
            if (idx < 392) excl_l[idx] = carry + incl - val;
            carry += __shfl(incl, 63, 64);
        }
    }
    __syncthreads();
    int v0 = b * BSZ;
    for (int vl = tid; vl < BSZ; vl += 256) {
        int v = v0 + vl;
        if (v < N_NODES) {
            start[v] = base + excl_l[vl];
            dinv[v] = rsqrtf((float)deg_l[vl] + 1.0f);
        }
    }
    if (b == NBUCK - 1 && tid == 0) start[N_NODES] = bucket_base[NBUCK];
    __syncthreads();
    for (int i = tid; i < 392; i += 256) deg_l[i] = 0;   // reuse as fill
    __syncthreads();
    for (int i = tid; i < m; i += 256) {
        unsigned int p = (unsigned int)part[base + i];
        unsigned int lc = p >> 17;
        int s = atomicAdd(&deg_l[lc], 1);
        csr[base + excl_l[lc] + s] = (int)(p & 0x1FFFFu);
    }
}

// ---- layer1 GEMM: gb[v,j] = bf16( dinv[v] * sum_k x[v,k]*W1[k,j] ) ----
__global__ __launch_bounds__(256) void k_gemm1(const float* __restrict__ x,
                                               const float* __restrict__ W,
                                               const float* __restrict__ dinv,
                                               bf16* __restrict__ gb) {
    __shared__ float Ws[64 * 64];
    __shared__ float xs[4][64];
    int tid = threadIdx.x;
    for (int i = tid; i < 64 * 64; i += 256) Ws[i] = W[i];
    int v0 = blockIdx.x * 4;
    for (int i = tid; i < 4 * 64; i += 256) xs[i >> 6][i & 63] = x[v0 * 64 + i];
    __syncthreads();
    int r = tid >> 6, j = tid & 63;
    float acc = 0.f;
#pragma unroll
    for (int k = 0; k < 64; k++) acc += xs[r][k] * Ws[k * 64 + j];
    int v = v0 + r;
    gb[v * 64 + j] = __float2bfloat16(acc * dinv[v]);
}

// ---- agg1: half-wave per edge, uint (2xbf16) gathers; bias+ReLU -> h ----
__global__ __launch_bounds__(256) void k_agg1(const int* __restrict__ csr,
                                              const int* __restrict__ start,
                                              const unsigned int* __restrict__ gb2,
                                              const float* __restrict__ dinv,
                                              const float* __restrict__ b1,
                                              float* __restrict__ h) {
    int lane = threadIdx.x & 63;
    int half = lane >> 5;
    int l = lane & 31;
    int v = blockIdx.x * 4 + (threadIdx.x >> 6);
    int s = start[v], e2 = start[v + 1];
    float ax = 0.f, ay = 0.f;
    if (half == 0) {
        unsigned int u = gb2[v * 32 + l];
        ax = bflo(u); ay = bfhi(u);
    }
    for (int base = s; base < e2; base += 64) {
        int cnt = e2 - base; if (cnt > 64) cnt = 64;
        int rl = (lane < cnt) ? csr[base + lane] : 0;
#pragma unroll 8
        for (int i = 0; i < 32; i++) {
            int idx = 2 * i + half;
            int r = __shfl(rl, idx, 64);
            if (idx < cnt) {
                unsigned int u = gb2[r * 32 + l];
                ax += bflo(u); ay += bfhi(u);
            }
        }
    }
    ax += __shfl_xor(ax, 32, 64);
    ay += __shfl_xor(ay, 32, 64);
    float d = dinv[v];
    float hx = d * ax + b1[2 * l];
    float hy = d * ay + b1[2 * l + 1];
    hx = hx > 0.f ? hx : 0.f;
    hy = hy > 0.f ? hy : 0.f;
    if (half == 0) ((float2*)(h + (size_t)v * 64))[l] = make_float2(hx, hy);
}

// ---- layer2 GEMM: g2b[v,j] = bf16( dinv[v] * sum_k h[v,k]*W2[k,j] ) ----
__global__ __launch_bounds__(256) void k_gemm2(const float* __restrict__ h,
                                               const float* __restrict__ W,
                                               const float* __restrict__ dinv,
                                               bf16* __restrict__ g2b) {
    __shared__ float Ws[64 * 40];
    __shared__ float hs[4][64];
    int tid = threadIdx.x;
    for (int i = tid; i < 64 * 40; i += 256) Ws[i] = W[i];
    int v0 = blockIdx.x * 4;
    for (int i = tid; i < 4 * 64; i += 256) hs[i >> 6][i & 63] = h[v0 * 64 + i];
    __syncthreads();
    int r = tid >> 6, j = tid & 63;
    if (j < 40) {
        float acc = 0.f;
#pragma unroll
        for (int k = 0; k < 64; k++) acc += hs[r][k] * Ws[k * 40 + j];
        int v = v0 + r;
        g2b[v * 40 + j] = __float2bfloat16(acc * dinv[v]);
    }
}

// ---- agg2: half-wave per edge; fused bias + log_softmax -> out ----
__global__ __launch_bounds__(256) void k_agg2(const int* __restrict__ csr,
                                              const int* __restrict__ start,
                                              const unsigned int* __restrict__ g2b2,
                                              const float* __restrict__ dinv,
                                              const float* __restrict__ b2v,
                                              float* __restrict__ out) {
    int lane = threadIdx.x & 63;
    int half = lane >> 5;
    int l = lane & 31;
    int v = blockIdx.x * 4 + (threadIdx.x >> 6);
    int s = start[v], e2 = start[v + 1];
    bool act = (l < 20);
    float ax = 0.f, ay = 0.f;
    if (half == 0 && act) {
        unsigned int u = g2b2[v * 20 + l];
        ax = bflo(u); ay = bfhi(u);
    }
    for (int base = s; base < e2; base += 64) {
        int cnt = e2 - base; if (cnt > 64) cnt = 64;
        int rl = (lane < cnt) ? csr[base + lane] : 0;
#pragma unroll 8
        for (int i = 0; i < 32; i++) {
            int idx = 2 * i + half;
            int r = __shfl(rl, idx, 64);
            if (act && idx < cnt) {
                unsigned int u = g2b2[r * 20 + l];
                ax += bflo(u); ay += bfhi(u);
            }
        }
    }
    ax += __shfl_xor(ax, 32, 64);
    ay += __shfl_xor(ay, 32, 64);
    float d = dinv[v];
    float lx = act ? d * ax + b2v[2 * l] : -INFINITY;
    float ly = act ? d * ay + b2v[2 * l + 1] : -INFINITY;
    float m = fmaxf(lx, ly);
#pragma unroll
    for (int o = 16; o > 0; o >>= 1) m = fmaxf(m, __shfl_xor(m, o, 64));
    float ex = act ? (expf(lx - m) + expf(ly - m)) : 0.f;
#pragma unroll
    for (int o = 16; o > 0; o >>= 1) ex += __shfl_xor(ex, o, 64);
    float lse = m + logf(ex);
    if (half == 0 && act)
        ((float2*)(out + (size_t)v * 40))[l] = make_float2(lx - lse, ly - lse);
}

extern "C" void kernel_launch(void* const* d_in, const int* in_sizes, int n_in,
                              void* d_out, int out_size, void* d_ws, size_t ws_size,
                              hipStream_t stream) {
    const float* x  = (const float*)d_in[0];
    const int*   ei = (const int*)d_in[1];
    const float* W1 = (const float*)d_in[2];
    const float* b1 = (const float*)d_in[3];
    const float* W2 = (const float*)d_in[4];
    const float* b2 = (const float*)d_in[5];
    float* out = (float*)d_out;

    const int N = N_NODES;
    // Workspace layout (ints from base), total ~52 MB:
    int*   part  = (int*)d_ws;                  // E      packed partitioned edges
    int*   csr   = part + N_EDGES;              // E
    int*   start = csr + N_EDGES;               // N+2 (padded even)
    int*   bcnt  = start + N + 2;               // 256*16 padded counters
    int*   fill  = bcnt + 4096;                 // 256*16 padded counters
    int*   bbase = fill + 4096;                 // 257 (+pad -> 258)
    float* dinv  = (float*)(bbase + 258);       // N
    float* h     = dinv + N;                    // N*64 fp32 (8B-aligned)
    bf16*  gb    = (bf16*)(h + (size_t)N * 64); // N*64 bf16 (g1; reused g2 N*40)

    k_zero<<<16, 256, 0, stream>>>(bcnt, 4096);
    k_cnt<<<256, 256, 0, stream>>>(ei + N_EDGES, bcnt);
    k_scan256<<<1, 256, 0, stream>>>(bcnt, fill, bbase);
    k_place<<<P3_GRID, 256, 0, stream>>>(ei, fill, part);
    k_build<<<NBUCK, 256, 0, stream>>>(part, bbase, start, dinv, csr);
    k_gemm1<<<N / 4, 256, 0, stream>>>(x, W1, dinv, gb);
    k_agg1<<<N / 4, 256, 0, stream>>>(csr, start, (const unsigned int*)gb, dinv, b1, h);
    k_gemm2<<<N / 4, 256, 0, stream>>>(h, W2, dinv, gb);
    k_agg2<<<N / 4, 256, 0, stream>>>(csr, start, (const unsigned int*)gb, dinv, b2, out);
}